// Round 1
// baseline (468.720 us; speedup 1.0000x reference)
//
#include <hip/hip_runtime.h>
#include <hip/hip_bf16.h>
#include <cstdint>
#include <cstddef>

typedef __bf16 bf16x8 __attribute__((ext_vector_type(8)));
typedef float f32x4 __attribute__((ext_vector_type(4)));
typedef unsigned short u16;

#define SEQ 2048
#define NH 16
#define HD 128
#define DMODEL 2048
#define NQKV 6144
#define NB 32     // seq blocks (2048/64)
#define KSEL 512  // top-k blocks per head

__device__ __forceinline__ u16 f2bf(float f) {
  unsigned u = __float_as_uint(f);
  u += 0x7fffu + ((u >> 16) & 1u);  // round-to-nearest-even
  return (u16)(u >> 16);
}
__device__ __forceinline__ float bf2f(u16 b) {
  return __uint_as_float(((unsigned)b) << 16);
}

// ---------------- fp32 -> bf16 convert (vectorized x4) ----------------
__global__ void convert_bf16_kernel(const float* __restrict__ in, u16* __restrict__ out, int n4) {
  int i = blockIdx.x * 256 + threadIdx.x;
  if (i < n4) {
    float4 v = ((const float4*)in)[i];
    ((ushort4*)out)[i] = make_ushort4(f2bf(v.x), f2bf(v.y), f2bf(v.z), f2bf(v.w));
  }
}

// ---------------- weight transpose+convert: W[2048][2048] fp32 -> W^T bf16 ----------------
__global__ void transpose_w_kernel(const float* __restrict__ in, u16* __restrict__ out) {
  __shared__ float tile[64][65];  // +1 pad: conflict-free column reads
  int c0 = blockIdx.x * 64, r0 = blockIdx.y * 64;
  int t = threadIdx.x;
  int c = t & 63, r4 = t >> 6;
  for (int i = 0; i < 16; ++i) {
    int r = r4 + i * 4;
    tile[r][c] = in[(size_t)(r0 + r) * 2048 + c0 + c];
  }
  __syncthreads();
  int rr = t & 63, c4 = t >> 6;
  for (int i = 0; i < 16; ++i) {
    int cc = c4 + i * 4;
    out[(size_t)(c0 + cc) * 2048 + r0 + rr] = f2bf(tile[rr][cc]);
  }
}

// ---------------- block mask: per-head top-512 by rank counting ----------------
__global__ void mask_kernel(const float* __restrict__ sp, int* __restrict__ sel_cnt,
                            int* __restrict__ sel_idx, unsigned* __restrict__ sel_mask) {
  __shared__ float vals[1024];
  __shared__ int selected[1024];
  int h = blockIdx.x, t = threadIdx.x;
  vals[t] = sp[h * 1024 + t];
  __syncthreads();
  float v = vals[t];
  int cnt = 0;
  for (int j = 0; j < 1024; ++j) cnt += vals[j] > v ? 1 : 0;
  // selected <=> strictly greater than 512th-largest <=> rank < 511
  selected[t] = (cnt < (KSEL - 1)) ? 1 : 0;
  __syncthreads();
  if (t < NB) {
    int n = 0; unsigned m = 0;
    for (int kb = 0; kb < NB; ++kb) {
      if (selected[t * NB + kb]) { sel_idx[(h * NB + t) * NB + n] = kb; ++n; m |= 1u << kb; }
    }
    sel_cnt[h * NB + t] = n;
    sel_mask[h * NB + t] = m;
  }
}

// ---------------- bf16 GEMM: C[m][n] = sum_k A[m][k] * Bt[n][k] ----------------
// 128x128 tile, BK=64, 256 threads (4 waves, 2x2), 16x16x32 MFMA, 4x4 acc/wave.
template <int WRITE_BF16>
__global__ __launch_bounds__(256, 2) void gemm_bt_kernel(
    const u16* __restrict__ A, const u16* __restrict__ Bt, void* __restrict__ Cout,
    int M, int N, int K) {
  __shared__ __align__(16) u16 As[128 * 72];  // rows padded 64->72 elems (144B): 2-way bank alias only
  __shared__ __align__(16) u16 Bs[128 * 72];
  const int t = threadIdx.x;
  const int lane = t & 63, w = t >> 6;
  const int wm = (w >> 1) * 64, wn = (w & 1) * 64;
  const int quad = lane >> 4, l16 = lane & 15;
  const int m0 = blockIdx.y * 128, n0 = blockIdx.x * 128;

  f32x4 acc[4][4] = {};

  for (int kt = 0; kt < K; kt += 64) {
    __syncthreads();  // previous iter's frag reads done before restaging
#pragma unroll
    for (int i = 0; i < 4; ++i) {
      int c = t + i * 256;          // 1024 16B-chunks per matrix
      int row = c >> 3, cr = c & 7; // 8 chunks per 64-elem row
      *(float4*)(&As[row * 72 + cr * 8]) =
          *(const float4*)(A + (size_t)(m0 + row) * K + kt + cr * 8);
      *(float4*)(&Bs[row * 72 + cr * 8]) =
          *(const float4*)(Bt + (size_t)(n0 + row) * K + kt + cr * 8);
    }
    __syncthreads();
#pragma unroll
    for (int ks = 0; ks < 2; ++ks) {
      bf16x8 af[4], bfr[4];
#pragma unroll
      for (int mt = 0; mt < 4; ++mt)
        af[mt] = *(const bf16x8*)(&As[(wm + mt * 16 + l16) * 72 + ks * 32 + quad * 8]);
#pragma unroll
      for (int nt = 0; nt < 4; ++nt)
        bfr[nt] = *(const bf16x8*)(&Bs[(wn + nt * 16 + l16) * 72 + ks * 32 + quad * 8]);
#pragma unroll
      for (int mt = 0; mt < 4; ++mt)
#pragma unroll
        for (int nt = 0; nt < 4; ++nt)
          acc[mt][nt] = __builtin_amdgcn_mfma_f32_16x16x32_bf16(af[mt], bfr[nt], acc[mt][nt], 0, 0, 0);
    }
  }
  // epilogue: C/D layout col=lane&15, row=quad*4+reg (m89-verified)
#pragma unroll
  for (int mt = 0; mt < 4; ++mt)
#pragma unroll
    for (int nt = 0; nt < 4; ++nt)
#pragma unroll
      for (int p = 0; p < 4; ++p) {
        int row = m0 + wm + mt * 16 + quad * 4 + p;
        int col = n0 + wn + nt * 16 + l16;
        if (WRITE_BF16)
          ((u16*)Cout)[(size_t)row * N + col] = f2bf(acc[mt][nt][p]);
        else
          ((float*)Cout)[(size_t)row * N + col] = acc[mt][nt][p];
      }
}

// ---------------- prep: RoPE on Q,K; V -> [h][d][s]; V block sums ----------------
__global__ __launch_bounds__(256, 2) void prep_kernel(
    const u16* __restrict__ QKVb, u16* __restrict__ Qh, u16* __restrict__ Kh,
    u16* __restrict__ Vt, float* __restrict__ Vbsum) {
  __shared__ float vtile[64][129];  // stride 129 words -> conflict-free column reads
  int sb = blockIdx.x, h = blockIdx.y;
  int s0 = sb * 64, t = threadIdx.x;
  int d = t & 127, rp = t >> 7;
  float inv_freq = powf(10000.0f, -(float)(2 * (d & 63)) / 128.0f);
  int dp = (d + 64) & 127;
  float sgn = (d < 64) ? -1.0f : 1.0f;
  for (int i = 0; i < 32; ++i) {
    int row = rp + i * 2;
    int s = s0 + row;
    const u16* base = QKVb + (size_t)s * NQKV + h * HD;
    float ang = (float)s * inv_freq;
    float cs = cosf(ang), sn = sinf(ang);
    float q = bf2f(base[d]), qp = bf2f(base[dp]);
    float k = bf2f(base[DMODEL + d]), kp = bf2f(base[DMODEL + dp]);
    Qh[((size_t)h * SEQ + s) * HD + d] = f2bf(q * cs + sgn * qp * sn);
    Kh[((size_t)h * SEQ + s) * HD + d] = f2bf(k * cs + sgn * kp * sn);
    vtile[row][d] = bf2f(base[2 * DMODEL + d]);
  }
  __syncthreads();
  int ss = t & 63, dg = t >> 6;
  for (int i = 0; i < 32; ++i) {
    int dd = dg + i * 4;
    Vt[((size_t)h * HD + dd) * SEQ + s0 + ss] = f2bf(vtile[ss][dd]);
  }
  if (t < HD) {
    float sum = 0.f;
    for (int r = 0; r < 64; ++r) sum += vtile[r][t];
    Vbsum[((size_t)h * NB + sb) * HD + t] = sum;
  }
}

// ---------------- block-sparse attention with exact zero-score correction ----------------
// scores at unselected blocks are exactly 0 (not -inf): softmax includes them.
// Flash over selected blocks with m initialized to 0 (exact by shift-invariance),
// then O += e^{-m} * sum_{unsel} V ; l += 64*(32-nsel) * e^{-m}.
__global__ __launch_bounds__(256, 2) void attn_kernel(
    const u16* __restrict__ Qh, const u16* __restrict__ Kh, const u16* __restrict__ Vt,
    const float* __restrict__ Vbsum, const int* __restrict__ sel_cnt,
    const int* __restrict__ sel_idx, const unsigned* __restrict__ sel_mask,
    u16* __restrict__ attnb) {
  __shared__ float vcorr[HD];
  __shared__ __align__(16) u16 pbuf[4][16 * 72];  // per-wave P transpose buffer
  int qb = blockIdx.x, h = blockIdx.y;
  int t = threadIdx.x, lane = t & 63, w = t >> 6;
  int quad = lane >> 4, l16 = lane & 15;
  int rowblk = h * NB + qb;
  int nsel = sel_cnt[rowblk];
  unsigned smask = sel_mask[rowblk];
  if (t < HD) {
    float c = 0.f;
    for (int kb = 0; kb < NB; ++kb)
      if (!((smask >> kb) & 1u)) c += Vbsum[((size_t)h * NB + kb) * HD + t];
    vcorr[t] = c;
  }
  __syncthreads();

  // Q fragments in registers: A-layout m=lane&15, k=quad*8+j (4 k-steps of 32)
  bf16x8 qf[4];
  {
    const u16* qbase = Qh + ((size_t)h * SEQ + qb * 64 + w * 16 + l16) * HD + quad * 8;
#pragma unroll
    for (int kk = 0; kk < 4; ++kk) qf[kk] = *(const bf16x8*)(qbase + kk * 32);
  }
  float mst[4] = {0.f, 0.f, 0.f, 0.f};  // m init 0: masked zero-scores in the max
  float lst[4] = {0.f, 0.f, 0.f, 0.f};
  f32x4 oacc[8] = {};
  const float scale = 0.08838834764831845f;  // 1/sqrt(128)
  u16* pb = pbuf[w];

  for (int si = 0; si < nsel; ++si) {
    int kb = sel_idx[rowblk * NB + si];
    const u16* kbase = Kh + ((size_t)h * SEQ + kb * 64) * HD;
    f32x4 sacc[4] = {};
#pragma unroll
    for (int kk = 0; kk < 4; ++kk) {
#pragma unroll
      for (int nt = 0; nt < 4; ++nt) {
        bf16x8 bfr = *(const bf16x8*)(kbase + (size_t)(nt * 16 + l16) * HD + kk * 32 + quad * 8);
        sacc[nt] = __builtin_amdgcn_mfma_f32_16x16x32_bf16(qf[kk], bfr, sacc[nt], 0, 0, 0);
      }
    }
    float nm[4], al[4], rsum[4];
#pragma unroll
    for (int p = 0; p < 4; ++p) {
      float mx = fmaxf(fmaxf(sacc[0][p], sacc[1][p]), fmaxf(sacc[2][p], sacc[3][p]));
      mx *= scale;
#pragma unroll
      for (int off = 1; off < 16; off <<= 1)
        mx = fmaxf(mx, __shfl_xor(mx, off, 64));  // reduce over 16 lanes of quad
      float m_new = fmaxf(mst[p], mx);
      nm[p] = m_new;
      al[p] = __expf(mst[p] - m_new);
      rsum[p] = 0.f;
    }
    __syncthreads();  // order this iter's pbuf writes after prev iter's reads
#pragma unroll
    for (int nt = 0; nt < 4; ++nt) {
#pragma unroll
      for (int p = 0; p < 4; ++p) {
        float pv = __expf(sacc[nt][p] * scale - nm[p]);
        u16 pr = f2bf(pv);
        pb[(quad * 4 + p) * 72 + nt * 16 + l16] = pr;  // C-layout -> [row][key] in LDS
        rsum[p] += bf2f(pr);                           // l consistent with rounded P
      }
    }
#pragma unroll
    for (int p = 0; p < 4; ++p) {
#pragma unroll
      for (int off = 1; off < 16; off <<= 1)
        rsum[p] += __shfl_xor(rsum[p], off, 64);
      lst[p] = lst[p] * al[p] + rsum[p];
      mst[p] = nm[p];
    }
#pragma unroll
    for (int d8 = 0; d8 < 8; ++d8)
#pragma unroll
      for (int p = 0; p < 4; ++p)
        oacc[d8][p] *= al[p];
    __syncthreads();  // pbuf writes visible before A-layout reads
    const u16* vbase = Vt + (size_t)h * HD * SEQ + kb * 64;
#pragma unroll
    for (int ks = 0; ks < 2; ++ks) {
      bf16x8 pf = *(const bf16x8*)(pb + l16 * 72 + ks * 32 + quad * 8);
#pragma unroll
      for (int nt = 0; nt < 8; ++nt) {
        bf16x8 vf = *(const bf16x8*)(vbase + (size_t)(nt * 16 + l16) * SEQ + ks * 32 + quad * 8);
        oacc[nt] = __builtin_amdgcn_mfma_f32_16x16x32_bf16(pf, vf, oacc[nt], 0, 0, 0);
      }
    }
  }
  int cntm = 64 * (NB - nsel);  // masked columns per row
#pragma unroll
  for (int p = 0; p < 4; ++p) {
    float e = __expf(-mst[p]);
    float lf = lst[p] + (float)cntm * e;
    float inv = 1.0f / lf;
    int row = qb * 64 + w * 16 + quad * 4 + p;
#pragma unroll
    for (int nt = 0; nt < 8; ++nt) {
      int dd = nt * 16 + l16;
      float o = (oacc[nt][p] + e * vcorr[dd]) * inv;
      attnb[(size_t)row * DMODEL + h * HD + dd] = f2bf(o);
    }
  }
}

extern "C" void kernel_launch(void* const* d_in, const int* in_sizes, int n_in,
                              void* d_out, int out_size, void* d_ws, size_t ws_size,
                              hipStream_t stream) {
  const float* hidden = (const float*)d_in[0];
  const float* q_w = (const float*)d_in[1];
  const float* k_w = (const float*)d_in[2];
  const float* v_w = (const float*)d_in[3];
  const float* o_w = (const float*)d_in[4];
  const float* sp  = (const float*)d_in[5];

  char* ws = (char*)d_ws;
  size_t off = 0;
  auto alloc = [&](size_t bytes) -> void* {
    void* p = ws + off;
    off += (bytes + 255) & ~(size_t)255;
    return p;
  };
  u16* Xb     = (u16*)alloc((size_t)SEQ * DMODEL * 2);          // 8 MB (reused as attnb)
  u16* Wqkvt  = (u16*)alloc((size_t)NQKV * DMODEL * 2);         // 25 MB
  u16* Wot    = (u16*)alloc((size_t)DMODEL * DMODEL * 2);       // 8 MB
  u16* QKVb   = (u16*)alloc((size_t)SEQ * NQKV * 2);            // 25 MB
  u16* Qh     = (u16*)alloc((size_t)NH * SEQ * HD * 2);         // 8 MB
  u16* Kh     = (u16*)alloc((size_t)NH * SEQ * HD * 2);         // 8 MB
  u16* Vt     = (u16*)alloc((size_t)NH * HD * SEQ * 2);         // 8 MB
  float* Vbsum = (float*)alloc((size_t)NH * NB * HD * 4);       // 256 KB
  int* sel_cnt = (int*)alloc(NH * NB * 4);
  int* sel_idx = (int*)alloc(NH * NB * NB * 4);
  unsigned* sel_mask = (unsigned*)alloc(NH * NB * 4);
  u16* attnb = Xb;  // Xb dead after QKV GEMM; attnb written after -> safe alias

  convert_bf16_kernel<<<4096, 256, 0, stream>>>(hidden, Xb, SEQ * DMODEL / 4);
  transpose_w_kernel<<<dim3(32, 32), 256, 0, stream>>>(q_w, Wqkvt);
  transpose_w_kernel<<<dim3(32, 32), 256, 0, stream>>>(k_w, Wqkvt + (size_t)DMODEL * 2048);
  transpose_w_kernel<<<dim3(32, 32), 256, 0, stream>>>(v_w, Wqkvt + (size_t)2 * DMODEL * 2048);
  transpose_w_kernel<<<dim3(32, 32), 256, 0, stream>>>(o_w, Wot);
  mask_kernel<<<NH, 1024, 0, stream>>>(sp, sel_cnt, sel_idx, sel_mask);

  gemm_bt_kernel<1><<<dim3(NQKV / 128, SEQ / 128), 256, 0, stream>>>(
      Xb, Wqkvt, QKVb, SEQ, NQKV, DMODEL);
  prep_kernel<<<dim3(NB, NH), 256, 0, stream>>>(QKVb, Qh, Kh, Vt, Vbsum);
  attn_kernel<<<dim3(NB, NH), 256, 0, stream>>>(Qh, Kh, Vt, Vbsum, sel_cnt, sel_idx,
                                                sel_mask, attnb);
  gemm_bt_kernel<0><<<dim3(DMODEL / 128, SEQ / 128), 256, 0, stream>>>(
      attnb, Wot, d_out, SEQ, DMODEL, DMODEL);
}

// Round 2
// 326.717 us; speedup vs baseline: 1.4346x; 1.4346x over previous
//
#include <hip/hip_runtime.h>
#include <hip/hip_bf16.h>
#include <cstdint>
#include <cstddef>

typedef __bf16 bf16x8 __attribute__((ext_vector_type(8)));
typedef float f32x4 __attribute__((ext_vector_type(4)));
typedef unsigned short u16;

#define SEQ 2048
#define NH 16
#define HD 128
#define DMODEL 2048
#define NQKV 6144
#define NB 32     // seq blocks (2048/64)
#define KSEL 512  // top-k blocks per head

__device__ __forceinline__ u16 f2bf(float f) {
  unsigned u = __float_as_uint(f);
  u += 0x7fffu + ((u >> 16) & 1u);  // round-to-nearest-even
  return (u16)(u >> 16);
}
__device__ __forceinline__ float bf2f(u16 b) {
  return __uint_as_float(((unsigned)b) << 16);
}

// Async global->LDS, 16B per lane. LDS dest = wave-uniform base + lane*16
// (m104/m108). Integer casts: generic LDS ptr low 32 bits == LDS offset;
// generic global ptr == AS1 value.
__device__ __forceinline__ void async_copy16(const void* g, void* l) {
  __builtin_amdgcn_global_load_lds(
      (__attribute__((address_space(1))) void*)(unsigned long long)g,
      (__attribute__((address_space(3))) void*)(unsigned)(unsigned long long)l,
      16, 0, 0);
}

// ---------------- fp32 -> bf16 convert (vectorized x4) ----------------
__global__ void convert_bf16_kernel(const float* __restrict__ in, u16* __restrict__ out, int n4) {
  int i = blockIdx.x * 256 + threadIdx.x;
  if (i < n4) {
    float4 v = ((const float4*)in)[i];
    ((ushort4*)out)[i] = make_ushort4(f2bf(v.x), f2bf(v.y), f2bf(v.z), f2bf(v.w));
  }
}

// ---------------- weight transpose+convert: W[2048][2048] fp32 -> W^T bf16 ----------------
__global__ void transpose_w_kernel(const float* __restrict__ in, u16* __restrict__ out) {
  __shared__ float tile[64][65];  // +1 pad: conflict-free column reads
  int c0 = blockIdx.x * 64, r0 = blockIdx.y * 64;
  int t = threadIdx.x;
  int c = t & 63, r4 = t >> 6;
  for (int i = 0; i < 16; ++i) {
    int r = r4 + i * 4;
    tile[r][c] = in[(size_t)(r0 + r) * 2048 + c0 + c];
  }
  __syncthreads();
  int rr = t & 63, c4 = t >> 6;
  for (int i = 0; i < 16; ++i) {
    int cc = c4 + i * 4;
    out[(size_t)(c0 + cc) * 2048 + r0 + rr] = f2bf(tile[rr][cc]);
  }
}

// ---------------- block mask: per-head top-512 by rank counting ----------------
__global__ void mask_kernel(const float* __restrict__ sp, int* __restrict__ sel_cnt,
                            int* __restrict__ sel_idx, unsigned* __restrict__ sel_mask) {
  __shared__ float vals[1024];
  __shared__ int selected[1024];
  int h = blockIdx.x, t = threadIdx.x;
  vals[t] = sp[h * 1024 + t];
  __syncthreads();
  float v = vals[t];
  int cnt = 0;
  for (int j = 0; j < 1024; ++j) cnt += vals[j] > v ? 1 : 0;
  // selected <=> strictly greater than 512th-largest <=> rank < 511
  selected[t] = (cnt < (KSEL - 1)) ? 1 : 0;
  __syncthreads();
  if (t < NB) {
    int n = 0; unsigned m = 0;
    for (int kb = 0; kb < NB; ++kb) {
      if (selected[t * NB + kb]) { sel_idx[(h * NB + t) * NB + n] = kb; ++n; m |= 1u << kb; }
    }
    sel_cnt[h * NB + t] = n;
    sel_mask[h * NB + t] = m;
  }
}

// ---------------- bf16 GEMM: C[m][n] = sum_k A[m][k] * Bt[n][k] ----------------
// m97 structure: 128x128 tile, BK=64, global_load_lds width=16 staging,
// XOR-swizzled LDS (no padding allowed with global_load_lds; swizzle keeps
// ds_read_b128 at 2-way bank alias = free per m136).
// LDS slot s (16B): row=s>>3, holds global chunk c=(s&7)^(row&7) of that row.
template <int WRITE_BF16>
__global__ __launch_bounds__(256, 2) void gemm_bt_kernel(
    const u16* __restrict__ A, const u16* __restrict__ Bt, void* __restrict__ Cout,
    int M, int N, int K) {
  __shared__ __align__(16) u16 As[8192];  // 128 rows x 64 elems, swizzled
  __shared__ __align__(16) u16 Bs[8192];
  const int t = threadIdx.x;
  const int lane = t & 63, w = t >> 6;
  const int wm = (w >> 1) * 64, wn = (w & 1) * 64;
  const int quad = lane >> 4, l16 = lane & 15;
  const int m0 = blockIdx.y * 128, n0 = blockIdx.x * 128;

  f32x4 acc[4][4] = {};

  for (int kt = 0; kt < K; kt += 64) {
    __syncthreads();  // previous iter's frag reads done before restaging
#pragma unroll
    for (int j = 0; j < 4; ++j) {
      int sl = w * 256 + j * 64 + lane;
      int row = sl >> 3, c = (sl & 7) ^ (row & 7);
      const u16* ga = A + (size_t)(m0 + row) * K + kt + c * 8;
      const u16* gb = Bt + (size_t)(n0 + row) * K + kt + c * 8;
      async_copy16(ga, &As[(size_t)(w * 256 + j * 64) * 8]);
      async_copy16(gb, &Bs[(size_t)(w * 256 + j * 64) * 8]);
    }
    __syncthreads();  // compiler drains vmcnt(0) here -> tile visible
#pragma unroll
    for (int ks = 0; ks < 2; ++ks) {
      bf16x8 af[4], bfr[4];
#pragma unroll
      for (int mt = 0; mt < 4; ++mt) {
        int row = wm + mt * 16 + l16;
        af[mt] = *(const bf16x8*)(&As[(row * 8 + ((ks * 4 + quad) ^ (l16 & 7))) * 8]);
      }
#pragma unroll
      for (int nt = 0; nt < 4; ++nt) {
        int row = wn + nt * 16 + l16;
        bfr[nt] = *(const bf16x8*)(&Bs[(row * 8 + ((ks * 4 + quad) ^ (l16 & 7))) * 8]);
      }
#pragma unroll
      for (int mt = 0; mt < 4; ++mt)
#pragma unroll
        for (int nt = 0; nt < 4; ++nt)
          acc[mt][nt] = __builtin_amdgcn_mfma_f32_16x16x32_bf16(af[mt], bfr[nt], acc[mt][nt], 0, 0, 0);
    }
  }
  // epilogue: C/D layout col=lane&15, row=quad*4+reg (m89-verified)
#pragma unroll
  for (int mt = 0; mt < 4; ++mt)
#pragma unroll
    for (int nt = 0; nt < 4; ++nt)
#pragma unroll
      for (int p = 0; p < 4; ++p) {
        int row = m0 + wm + mt * 16 + quad * 4 + p;
        int col = n0 + wn + nt * 16 + l16;
        if (WRITE_BF16)
          ((u16*)Cout)[(size_t)row * N + col] = f2bf(acc[mt][nt][p]);
        else
          ((float*)Cout)[(size_t)row * N + col] = acc[mt][nt][p];
      }
}

// ---------------- prep: RoPE on Q,K; V -> [h][d][s]; V block sums ----------------
__global__ __launch_bounds__(256, 2) void prep_kernel(
    const u16* __restrict__ QKVb, u16* __restrict__ Qh, u16* __restrict__ Kh,
    u16* __restrict__ Vt, float* __restrict__ Vbsum) {
  __shared__ float vtile[64][129];  // stride 129 words -> conflict-free column reads
  int sb = blockIdx.x, h = blockIdx.y;
  int s0 = sb * 64, t = threadIdx.x;
  int d = t & 127, rp = t >> 7;
  float inv_freq = powf(10000.0f, -(float)(2 * (d & 63)) / 128.0f);
  int dp = (d + 64) & 127;
  float sgn = (d < 64) ? -1.0f : 1.0f;
  for (int i = 0; i < 32; ++i) {
    int row = rp + i * 2;
    int s = s0 + row;
    const u16* base = QKVb + (size_t)s * NQKV + h * HD;
    float ang = (float)s * inv_freq;
    float cs = cosf(ang), sn = sinf(ang);
    float q = bf2f(base[d]), qp = bf2f(base[dp]);
    float k = bf2f(base[DMODEL + d]), kp = bf2f(base[DMODEL + dp]);
    Qh[((size_t)h * SEQ + s) * HD + d] = f2bf(q * cs + sgn * qp * sn);
    Kh[((size_t)h * SEQ + s) * HD + d] = f2bf(k * cs + sgn * kp * sn);
    vtile[row][d] = bf2f(base[2 * DMODEL + d]);
  }
  __syncthreads();
  int ss = t & 63, dg = t >> 6;
  for (int i = 0; i < 32; ++i) {
    int dd = dg + i * 4;
    Vt[((size_t)h * HD + dd) * SEQ + s0 + ss] = f2bf(vtile[ss][dd]);
  }
  if (t < HD) {
    float sum = 0.f;
    for (int r = 0; r < 64; ++r) sum += vtile[r][t];
    Vbsum[((size_t)h * NB + sb) * HD + t] = sum;
  }
}

// ---------------- block-sparse attention, LDS-staged K/V ----------------
// Exact zero-score softmax correction as before. New: K double-buffered +
// V staged via global_load_lds (shared by all 4 waves -> 4x traffic cut);
// XOR-swizzled LDS layouts; 2 barriers/iter:
//   [B] after V-stage issue + QK + softmax  -> V ready & pbuf visible
//   [C] after PV                            -> Vs/Ks reusable next iter
// K prefetch for si+1 issued at loop top overlaps the whole QK phase.
__global__ __launch_bounds__(256, 2) void attn_kernel(
    const u16* __restrict__ Qh, const u16* __restrict__ Kh, const u16* __restrict__ Vt,
    const float* __restrict__ Vbsum, const int* __restrict__ sel_cnt,
    const int* __restrict__ sel_idx, const unsigned* __restrict__ sel_mask,
    u16* __restrict__ attnb) {
  __shared__ __align__(16) u16 Ks[2][8192];  // 64 rows x 128 elems (16 chunks), swizzle c^(r&15)
  __shared__ __align__(16) u16 Vs[8192];     // 128 d-rows x 64 elems (8 chunks), swizzle c^(d&7)
  __shared__ __align__(16) u16 pbuf[4][16 * 72];  // per-wave P transpose buffer
  __shared__ float vcorr[HD];
  // XCD swizzle: 2 heads per XCD -> per-XCD K/V working set 2MB <= 4MB L2.
  int bid = blockIdx.x;
  int h = (bid & 7) * 2 + ((bid >> 3) >> 5);
  int qb = (bid >> 3) & 31;
  int t = threadIdx.x, lane = t & 63, w = t >> 6;
  int quad = lane >> 4, l16 = lane & 15;
  int rowblk = h * NB + qb;
  int nsel = sel_cnt[rowblk];
  unsigned smask = sel_mask[rowblk];
  const int* selrow = sel_idx + rowblk * NB;

  auto stageK = [&](int buf, int kb) {
    const u16* kbase = Kh + ((size_t)h * SEQ + kb * 64) * HD;
#pragma unroll
    for (int j = 0; j < 4; ++j) {
      int s = w * 256 + j * 64 + lane;
      int r = s >> 4, c = (s & 15) ^ (r & 15);
      async_copy16(kbase + (size_t)r * HD + c * 8, &Ks[buf][(w * 256 + j * 64) * 8]);
    }
  };
  auto stageV = [&](int kb) {
    const u16* vbase = Vt + (size_t)h * HD * SEQ + kb * 64;
#pragma unroll
    for (int j = 0; j < 4; ++j) {
      int s = w * 256 + j * 64 + lane;
      int d = s >> 3, c = (s & 7) ^ (d & 7);
      async_copy16(vbase + (size_t)d * SEQ + c * 8, &Vs[(w * 256 + j * 64) * 8]);
    }
  };

  int kb_cur = (nsel > 0) ? selrow[0] : 0;
  if (nsel > 0) stageK(0, kb_cur);

  if (t < HD) {
    float c = 0.f;
    for (int kb = 0; kb < NB; ++kb)
      if (!((smask >> kb) & 1u)) c += Vbsum[((size_t)h * NB + kb) * HD + t];
    vcorr[t] = c;
  }
  // Q fragments in registers: A-layout m=lane&15, k=quad*8+j (4 k-steps of 32)
  bf16x8 qf[4];
  {
    const u16* qbase = Qh + ((size_t)h * SEQ + qb * 64 + w * 16 + l16) * HD + quad * 8;
#pragma unroll
    for (int kk = 0; kk < 4; ++kk) qf[kk] = *(const bf16x8*)(qbase + kk * 32);
  }
  float mst[4] = {0.f, 0.f, 0.f, 0.f};  // m init 0: masked zero-scores in the max
  float lst[4] = {0.f, 0.f, 0.f, 0.f};
  f32x4 oacc[8] = {};
  const float scale = 0.08838834764831845f;  // 1/sqrt(128)
  u16* pb = pbuf[w];
  int kb_n1 = (nsel > 1) ? selrow[1] : 0;

  __syncthreads();  // vcorr visible; stageK(0) drained

  for (int si = 0; si < nsel; ++si) {
    int cur = si & 1;
    int kb_n2 = (si + 2 < nsel) ? selrow[si + 2] : 0;  // loaded early, used next iter
    if (si + 1 < nsel) stageK(1 - cur, kb_n1);         // prefetch next K
    stageV(kb_cur);                                    // V for this iter (ready at [B])

    // QK^T from Ks[cur] (staged last iter, drained at [C]/prologue barrier)
    f32x4 sacc[4] = {};
#pragma unroll
    for (int kk = 0; kk < 4; ++kk) {
#pragma unroll
      for (int nt = 0; nt < 4; ++nt) {
        int row = nt * 16 + l16;
        bf16x8 bfr = *(const bf16x8*)(&Ks[cur][(row * 16 + ((kk * 4 + quad) ^ l16)) * 8]);
        sacc[nt] = __builtin_amdgcn_mfma_f32_16x16x32_bf16(qf[kk], bfr, sacc[nt], 0, 0, 0);
      }
    }
    float nm[4], al[4], rsum[4];
#pragma unroll
    for (int p = 0; p < 4; ++p) {
      float mx = fmaxf(fmaxf(sacc[0][p], sacc[1][p]), fmaxf(sacc[2][p], sacc[3][p]));
      mx *= scale;
#pragma unroll
      for (int off = 1; off < 16; off <<= 1)
        mx = fmaxf(mx, __shfl_xor(mx, off, 64));  // reduce over 16 lanes of quad
      float m_new = fmaxf(mst[p], mx);
      nm[p] = m_new;
      al[p] = __expf(mst[p] - m_new);
      rsum[p] = 0.f;
    }
#pragma unroll
    for (int nt = 0; nt < 4; ++nt) {
#pragma unroll
      for (int p = 0; p < 4; ++p) {
        float pv = __expf(sacc[nt][p] * scale - nm[p]);
        u16 pr = f2bf(pv);
        pb[(quad * 4 + p) * 72 + nt * 16 + l16] = pr;  // C-layout -> [row][key] in LDS
        rsum[p] += bf2f(pr);                           // l consistent with rounded P
      }
    }
#pragma unroll
    for (int p = 0; p < 4; ++p) {
#pragma unroll
      for (int off = 1; off < 16; off <<= 1)
        rsum[p] += __shfl_xor(rsum[p], off, 64);
      lst[p] = lst[p] * al[p] + rsum[p];
      mst[p] = nm[p];
    }
#pragma unroll
    for (int d8 = 0; d8 < 8; ++d8)
#pragma unroll
      for (int p = 0; p < 4; ++p)
        oacc[d8][p] *= al[p];

    __syncthreads();  // [B] V staged (vmcnt drained) + pbuf writes visible

#pragma unroll
    for (int ks2 = 0; ks2 < 2; ++ks2) {
      bf16x8 pf = *(const bf16x8*)(pb + l16 * 72 + ks2 * 32 + quad * 8);
#pragma unroll
      for (int nt = 0; nt < 8; ++nt) {
        int d = nt * 16 + l16;
        bf16x8 vf = *(const bf16x8*)(&Vs[(d * 8 + ((ks2 * 4 + quad) ^ (d & 7))) * 8]);
        oacc[nt] = __builtin_amdgcn_mfma_f32_16x16x32_bf16(pf, vf, oacc[nt], 0, 0, 0);
      }
    }
    __syncthreads();  // [C] Vs/pbuf reads done; Ks prefetch drained for next iter
    kb_cur = kb_n1;
    kb_n1 = kb_n2;
  }
  int cntm = 64 * (NB - nsel);  // masked columns per row
#pragma unroll
  for (int p = 0; p < 4; ++p) {
    float e = __expf(-mst[p]);
    float lf = lst[p] + (float)cntm * e;
    float inv = 1.0f / lf;
    int row = qb * 64 + w * 16 + quad * 4 + p;
#pragma unroll
    for (int nt = 0; nt < 8; ++nt) {
      int dd = nt * 16 + l16;
      float o = (oacc[nt][p] + e * vcorr[dd]) * inv;
      attnb[(size_t)row * DMODEL + h * HD + dd] = f2bf(o);
    }
  }
}

extern "C" void kernel_launch(void* const* d_in, const int* in_sizes, int n_in,
                              void* d_out, int out_size, void* d_ws, size_t ws_size,
                              hipStream_t stream) {
  const float* hidden = (const float*)d_in[0];
  const float* q_w = (const float*)d_in[1];
  const float* k_w = (const float*)d_in[2];
  const float* v_w = (const float*)d_in[3];
  const float* o_w = (const float*)d_in[4];
  const float* sp  = (const float*)d_in[5];

  char* ws = (char*)d_ws;
  size_t off = 0;
  auto alloc = [&](size_t bytes) -> void* {
    void* p = ws + off;
    off += (bytes + 255) & ~(size_t)255;
    return p;
  };
  u16* Xb     = (u16*)alloc((size_t)SEQ * DMODEL * 2);          // 8 MB (reused as attnb)
  u16* Wqkvt  = (u16*)alloc((size_t)NQKV * DMODEL * 2);         // 25 MB
  u16* Wot    = (u16*)alloc((size_t)DMODEL * DMODEL * 2);       // 8 MB
  u16* QKVb   = (u16*)alloc((size_t)SEQ * NQKV * 2);            // 25 MB
  u16* Qh     = (u16*)alloc((size_t)NH * SEQ * HD * 2);         // 8 MB
  u16* Kh     = (u16*)alloc((size_t)NH * SEQ * HD * 2);         // 8 MB
  u16* Vt     = (u16*)alloc((size_t)NH * HD * SEQ * 2);         // 8 MB
  float* Vbsum = (float*)alloc((size_t)NH * NB * HD * 4);       // 256 KB
  int* sel_cnt = (int*)alloc(NH * NB * 4);
  int* sel_idx = (int*)alloc(NH * NB * NB * 4);
  unsigned* sel_mask = (unsigned*)alloc(NH * NB * 4);
  u16* attnb = Xb;  // Xb dead after QKV GEMM; attnb written after -> safe alias

  convert_bf16_kernel<<<4096, 256, 0, stream>>>(hidden, Xb, SEQ * DMODEL / 4);
  transpose_w_kernel<<<dim3(32, 32), 256, 0, stream>>>(q_w, Wqkvt);
  transpose_w_kernel<<<dim3(32, 32), 256, 0, stream>>>(k_w, Wqkvt + (size_t)DMODEL * 2048);
  transpose_w_kernel<<<dim3(32, 32), 256, 0, stream>>>(v_w, Wqkvt + (size_t)2 * DMODEL * 2048);
  transpose_w_kernel<<<dim3(32, 32), 256, 0, stream>>>(o_w, Wot);
  mask_kernel<<<NH, 1024, 0, stream>>>(sp, sel_cnt, sel_idx, sel_mask);

  gemm_bt_kernel<1><<<dim3(NQKV / 128, SEQ / 128), 256, 0, stream>>>(
      Xb, Wqkvt, QKVb, SEQ, NQKV, DMODEL);
  prep_kernel<<<dim3(NB, NH), 256, 0, stream>>>(QKVb, Qh, Kh, Vt, Vbsum);
  attn_kernel<<<512, 256, 0, stream>>>(Qh, Kh, Vt, Vbsum, sel_cnt, sel_idx,
                                       sel_mask, attnb);
  gemm_bt_kernel<0><<<dim3(DMODEL / 128, SEQ / 128), 256, 0, stream>>>(
      attnb, Wot, d_out, SEQ, DMODEL, DMODEL);
}